// Round 15
// baseline (182.152 us; speedup 1.0000x reference)
//
#include <hip/hip_runtime.h>
#include <hip/hip_bf16.h>

// B=4, S=2048, D=1024, H=16, HD=64, causal MHA forward, fp32 in/out.
// Pipeline: convert-W -> 3 QKV GEMMs (fp32 A, 2-deep reg prefetch) ->
//           flash attn (128-kv rounds, 4 q-tiles/block) -> out GEMM.

#define SLEN 2048
#define DMOD 1024

typedef __attribute__((ext_vector_type(8))) short s16x8;   // 8 bf16 (4 VGPRs)
typedef __attribute__((ext_vector_type(4))) float f32x4;

__device__ __forceinline__ unsigned short f2bf(float f) {
    union { __hip_bfloat16 h; unsigned short u; } cv;
    cv.h = __float2bfloat16(f);
    return cv.u;
}
__device__ __forceinline__ unsigned cvtpk(float a, float b) {
    unsigned r;
    asm("v_cvt_pk_bf16_f32 %0, %1, %2" : "=v"(r) : "v"(a), "v"(b));
    return r;
}
__device__ __forceinline__ void gload_lds16(const void* g, void* l) {
    __builtin_amdgcn_global_load_lds(
        (const __attribute__((address_space(1))) void*)g,
        (__attribute__((address_space(3))) void*)l, 16, 0, 0);
}

// ---------------- fp32 -> bf16 convert (weights only) --------------------
__global__ __launch_bounds__(256) void convert_w(
    const float* __restrict__ wq, const float* __restrict__ wk,
    const float* __restrict__ wv, const float* __restrict__ wo,
    unsigned short* __restrict__ dst)
{
    const int bid = blockIdx.x, tid = threadIdx.x;
    const int w = bid >> 7;
    const float* src = (w == 0) ? wq : (w == 1) ? wk : (w == 2) ? wv : wo;
    unsigned short* d = dst + (size_t)w * 1048576;
    const size_t off = (size_t)(bid & 127) * 8192;
#pragma unroll
    for (int i = 0; i < 8; ++i) {
        const size_t e = off + (size_t)(i * 256 + tid) * 4;
        float4 x = *reinterpret_cast<const float4*>(&src[e]);
        uint2 u;
        u.x = cvtpk(x.x, x.y);
        u.y = cvtpk(x.z, x.w);
        *reinterpret_cast<uint2*>(&d[e]) = u;
    }
}

// ---------------- QKV GEMM v2: 2-deep A prefetch -------------------------
// A fp32 direct; W bf16 DMA. Per pair of K-steps: loads for t+2 issue at t,
// cvt+ds_write at end of t+1 -> ~2 K-steps of latency cover.
template<int MODE>
__global__ __launch_bounds__(256, 2) void gemm_qkv(
    const float* __restrict__ A, const unsigned short* __restrict__ W,
    const float* __restrict__ bias, unsigned short* __restrict__ outp,
    float oscale)
{
    __shared__ unsigned short Asm[2][8192];
    __shared__ unsigned short Bsm[2][8192];

    const int tid  = threadIdx.x;
    const int lane = tid & 63, wid = tid >> 6;
    const int l15 = lane & 15, lhi = lane >> 4;

    const int flat = blockIdx.x;
    const int logical = (flat & 7) * 64 + (flat >> 3);
    const int m0 = (logical >> 3) * 128, n0 = (logical & 7) * 128;
    const int wr = wid >> 1, wc = wid & 1;

    int soff[4];
    const float* aptc[4];
#pragma unroll
    for (int i = 0; i < 4; ++i) {
        const int f = i * 256 + tid;
        const int srow = f >> 3, sg = f & 7;
        soff[i] = srow * 128 + ((sg ^ (srow & 7)) * 16);
        aptc[i] = A + (size_t)(m0 + srow) * 1024 + sg * 8;
    }
    const int wsrow = lane >> 3;
    const int wsgr  = (lane & 7) ^ wsrow;
    const unsigned short* bpt = W + (size_t)(n0 + wid * 8 + wsrow) * 1024 + wsgr * 8;

    int aoff[2][4], boff[2][4];
#pragma unroll
    for (int kk = 0; kk < 2; ++kk)
#pragma unroll
        for (int i = 0; i < 4; ++i) {
            const int s = ((4 * kk + lhi) ^ (l15 & 7)) * 16;
            aoff[kk][i] = (wr * 64 + i * 16 + l15) * 128 + s;
            boff[kk][i] = (wc * 64 + i * 16 + l15) * 128 + s;
        }

    f32x4 acc[4][4];
#pragma unroll
    for (int i = 0; i < 4; ++i)
#pragma unroll
        for (int j = 0; j < 4; ++j) acc[i][j] = (f32x4)0.f;

    float4 awE[8], awO[8];                     // two in-flight A tiles

    auto loadTo = [&](float4 (&aw)[8], int k0) {
#pragma unroll
        for (int i = 0; i < 4; ++i) {
            aw[2 * i]     = *reinterpret_cast<const float4*>(aptc[i] + k0);
            aw[2 * i + 1] = *reinterpret_cast<const float4*>(aptc[i] + k0 + 4);
        }
    };
    auto writeFrom = [&](float4 (&aw)[8], int bsel) {
#pragma unroll
        for (int i = 0; i < 4; ++i) {
            uint4 u;
            u.x = cvtpk(aw[2 * i].x,     aw[2 * i].y);
            u.y = cvtpk(aw[2 * i].z,     aw[2 * i].w);
            u.z = cvtpk(aw[2 * i + 1].x, aw[2 * i + 1].y);
            u.w = cvtpk(aw[2 * i + 1].z, aw[2 * i + 1].w);
            *reinterpret_cast<uint4*>((char*)&Asm[bsel][0] + soff[i]) = u;
        }
    };
    auto stageW = [&](int bsel) {
        char* bd = (char*)Bsm + bsel * 16384 + wid * 1024;
#pragma unroll
        for (int i = 0; i < 4; ++i)
            gload_lds16(bpt + i * 32768, bd + i * 4096);
        bpt += 64;
    };
    auto mfmaPhase = [&](const char* AB, const char* BB) {
#pragma unroll
        for (int kk = 0; kk < 2; ++kk) {
            s16x8 af[4], bfv[4];
#pragma unroll
            for (int i = 0; i < 4; ++i) af[i]  = *reinterpret_cast<const s16x8*>(AB + aoff[kk][i]);
#pragma unroll
            for (int j = 0; j < 4; ++j) bfv[j] = *reinterpret_cast<const s16x8*>(BB + boff[kk][j]);
#pragma unroll
            for (int i = 0; i < 4; ++i)
#pragma unroll
                for (int j = 0; j < 4; ++j)
                    acc[i][j] = __builtin_amdgcn_mfma_f32_16x16x32_bf16(af[i], bfv[j], acc[i][j], 0, 0, 0);
        }
    };

    // prologue: tile0 staged+written, tile1 loads in flight
    loadTo(awE, 0);
    stageW(0);
    writeFrom(awE, 0);
    loadTo(awO, 64);
    __syncthreads();

#pragma unroll 1
    for (int kt = 0; kt < 16; kt += 2) {
        // even step: compute tile kt (buf0)
        if (kt + 2 < 16) loadTo(awE, (kt + 2) * 64);
        if (kt + 1 < 16) stageW(1);
        mfmaPhase((const char*)&Asm[0][0], (const char*)&Bsm[0][0]);
        if (kt + 1 < 16) writeFrom(awO, 1);
        __syncthreads();
        // odd step: compute tile kt+1 (buf1)
        if (kt + 3 < 16) loadTo(awO, (kt + 3) * 64);
        if (kt + 2 < 16) stageW(0);
        mfmaPhase((const char*)&Asm[1][0], (const char*)&Bsm[1][0]);
        if (kt + 2 < 16) writeFrom(awE, 0);
        __syncthreads();
    }

#pragma unroll
    for (int j = 0; j < 4; ++j) {
        const int col = n0 + wc * 64 + j * 16 + l15;
        const float bv = bias[col];
#pragma unroll
        for (int i = 0; i < 4; ++i) {
#pragma unroll
            for (int r = 0; r < 4; ++r) {
                const int row = m0 + wr * 64 + i * 16 + lhi * 4 + r;
                const float val = (acc[i][j][r] + bv) * oscale;
                if constexpr (MODE == 0) {
                    outp[(size_t)((row >> 11) * 16 + (col >> 6)) * 131072
                         + (size_t)(row & 2047) * 64 + (col & 63)] = f2bf(val);
                } else {
                    outp[(size_t)((row >> 11) * 16 + (col >> 6)) * 131072
                         + (size_t)(col & 63) * 2048 + (row & 2047)] = f2bf(val);
                }
            }
        }
    }
}

// ---------------- out-proj GEMM (bf16 A via DMA, fp32 out) ---------------
__global__ __launch_bounds__(256) void gemm_out(
    const unsigned short* __restrict__ A, const unsigned short* __restrict__ W,
    const float* __restrict__ bias, float* __restrict__ outp)
{
    __shared__ unsigned short Asm[2][8192];
    __shared__ unsigned short Bsm[2][8192];

    const int tid  = threadIdx.x;
    const int lane = tid & 63, wid = tid >> 6;
    const int l15 = lane & 15, lhi = lane >> 4;

    const int flat = blockIdx.x;
    const int logical = (flat & 7) * 64 + (flat >> 3);
    const int m0 = (logical >> 3) * 128, n0 = (logical & 7) * 128;

    const int wr = wid >> 1, wc = wid & 1;
    const int srow = lane >> 3;
    const int sgr  = (lane & 7) ^ srow;

    int aoff[2][4], boff[2][4];
#pragma unroll
    for (int kk = 0; kk < 2; ++kk)
#pragma unroll
        for (int i = 0; i < 4; ++i) {
            const int s = ((4 * kk + lhi) ^ (l15 & 7)) * 16;
            aoff[kk][i] = (wr * 64 + i * 16 + l15) * 128 + s;
            boff[kk][i] = (wc * 64 + i * 16 + l15) * 128 + s;
        }

    const unsigned short* apt = A + (size_t)(m0 + wid * 8 + srow) * 1024 + sgr * 8;
    const unsigned short* bpt = W + (size_t)(n0 + wid * 8 + srow) * 1024 + sgr * 8;

    f32x4 acc[4][4];
#pragma unroll
    for (int i = 0; i < 4; ++i)
#pragma unroll
        for (int j = 0; j < 4; ++j) acc[i][j] = (f32x4)0.f;

    auto stage = [&](int bsel) {
        char* ad = (char*)Asm + bsel * 16384 + wid * 1024;
        char* bd = (char*)Bsm + bsel * 16384 + wid * 1024;
#pragma unroll
        for (int i = 0; i < 4; ++i) {
            gload_lds16(apt + i * 32768, ad + i * 4096);
            gload_lds16(bpt + i * 32768, bd + i * 4096);
        }
        apt += 64; bpt += 64;
    };

    stage(0);
    __syncthreads();
    int cur = 0;
#pragma unroll 1
    for (int kt = 0; kt < 16; ++kt) {
        if (kt < 15) stage(cur ^ 1);
        const char* AB = (const char*)Asm + cur * 16384;
        const char* BB = (const char*)Bsm + cur * 16384;
#pragma unroll
        for (int kk = 0; kk < 2; ++kk) {
            s16x8 af[4], bfv[4];
#pragma unroll
            for (int i = 0; i < 4; ++i) af[i]  = *reinterpret_cast<const s16x8*>(AB + aoff[kk][i]);
#pragma unroll
            for (int j = 0; j < 4; ++j) bfv[j] = *reinterpret_cast<const s16x8*>(BB + boff[kk][j]);
#pragma unroll
            for (int i = 0; i < 4; ++i)
#pragma unroll
                for (int j = 0; j < 4; ++j)
                    acc[i][j] = __builtin_amdgcn_mfma_f32_16x16x32_bf16(af[i], bfv[j], acc[i][j], 0, 0, 0);
        }
        __syncthreads();
        cur ^= 1;
    }

#pragma unroll
    for (int j = 0; j < 4; ++j) {
        const int col = n0 + wc * 64 + j * 16 + l15;
        const float bv = bias[col];
#pragma unroll
        for (int i = 0; i < 4; ++i)
#pragma unroll
            for (int r = 0; r < 4; ++r) {
                const int row = m0 + wr * 64 + i * 16 + lhi * 4 + r;
                outp[(size_t)row * 1024 + col] = acc[i][j][r] + bv;
            }
    }
}

// ---------------- flash attention v11 ------------------------------------
// 512 blocks; block (bh, bx<8) owns q-tiles {bx, 15-bx, 16+bx, 31-bx}.
// Rounds stage 128 kv rows as two 64x64 subtiles (layouts identical to v10).
// nt = ceil((32-bx)/2) in [13,16] -> max rounds halved vs v10. Up to 8
// independent subtile-computes per barrier. Fixed-shift softmax; l via
// ones-MFMA; Q pre-scaled by EXPC at projection.
#define EXPC 0.18033688011112043f   // 0.125 * log2(e)

__global__ __launch_bounds__(256, 2) void attn_kernel(
    const unsigned short* __restrict__ Q,
    const unsigned short* __restrict__ Kc,
    const unsigned short* __restrict__ Vt,
    unsigned short* __restrict__ Ao)
{
    // [0,32K): K dbuf (cur*16K + st*8K, each [64 kv][64 d] swizzled)
    // [32K,64K): V^T dbuf (same indexing, each [64 d][64 kv])
    // [64K,72K): per-wave P
    __shared__ char smem[73728];

    const int tid = threadIdx.x, lane = tid & 63, wid = tid >> 6;
    const int l15 = lane & 15, lhi = lane >> 4;
    const int sK = l15 & 7;
    const int sub = lane >> 3, c8s = lane & 7;
    const int thr = wid * 16 + l15;            // tile-local causal threshold

    const int kb0 = l15 * 128 + (lhi ^ sK) * 16;
    const int kb1 = kb0 ^ 64;
    char* const pb0 = smem + 65536 + wid * 2048 + kb0;
    char* const pb1 = smem + 65536 + wid * 2048 + kb1;
    char* const PWp = smem + 65536 + wid * 2048;
    int pw[4];
#pragma unroll
    for (int nb = 0; nb < 4; ++nb)
        pw[nb] = (l15 * 16 + ((nb * 4 + lhi) ^ (2 * sK))) * 8;

    // XCD swizzle over 512 blocks: each XCD owns 8 consecutive bh (all bx).
    const int flat = blockIdx.x;
    const int logical = (flat & 7) * 64 + (flat >> 3);
    const int bx = logical & 7, bh = logical >> 3;
    const int qts[4] = {bx, 15 - bx, 16 + bx, 31 - bx};

    const size_t base = (size_t)bh * SLEN * 64;
    const unsigned short* Qb = Q + base;
    const unsigned short* Kb = Kc + base;
    const unsigned short* Vb = Vt + base;      // [64][SLEN]
    const int b = bh >> 4, h = bh & 15;
    const int scol = (c8s ^ sub) * 8;

    const f32x4 fzero = (f32x4)0.f;
    const s16x8 onesb = (s16x8)(short)0x3F80;  // bf16 1.0 splat

    s16x8 aq[4][2];
    f32x4 oA[4][4], lA[4];
#pragma unroll
    for (int j = 0; j < 4; ++j) {
#pragma unroll
        for (int kk = 0; kk < 2; ++kk)
            aq[j][kk] = *reinterpret_cast<const s16x8*>(
                &Qb[(size_t)(qts[j] * 64 + wid * 16 + l15) * 64 + kk * 32 + 8 * lhi]);
#pragma unroll
        for (int nb = 0; nb < 4; ++nb) oA[j][nb] = (f32x4)0.f;
        lA[j] = (f32x4)0.f;
    }

    const unsigned short* kpt = Kb + (16 * wid + sub) * 64 + scol;
    const unsigned short* vpt = Vb + (size_t)(16 * wid + sub) * SLEN + scol;

    // stage one 128-kv round (two 64x64 subtiles of K and V^T)
    auto stage = [&](int bsel) {
        char* kd = smem + bsel * 16384 + wid * 2048;
        char* vd = smem + 32768 + bsel * 16384 + wid * 2048;
        gload_lds16(kpt,                kd);
        gload_lds16(kpt + 512,          kd + 1024);
        gload_lds16(kpt + 4096,         kd + 8192);          // K subtile 1 (+64 rows)
        gload_lds16(kpt + 4096 + 512,   kd + 8192 + 1024);
        gload_lds16(vpt,                vd);
        gload_lds16(vpt + 16384,        vd + 1024);
        gload_lds16(vpt + 64,           vd + 8192);          // V subtile 1 (+64 cols)
        gload_lds16(vpt + 16384 + 64,   vd + 8192 + 1024);
        kpt += 8192; vpt += 128;
    };

    // one q-tile vs one 64-kv subtile (V at K-base + 32768)
    auto tile = [&](const s16x8 (&aqj)[2], f32x4 (&o_acc)[4], f32x4& l_acc,
                    bool domask, const char* c0, const char* c1) {
        f32x4 sc2[4];
        __builtin_amdgcn_s_setprio(1);
        {
            s16x8 ak[4];
#pragma unroll
            for (int nb = 0; nb < 4; ++nb)
                ak[nb] = *reinterpret_cast<const s16x8*>(c0 + nb * 2048);
#pragma unroll
            for (int nb = 0; nb < 4; ++nb)
                sc2[nb] = __builtin_amdgcn_mfma_f32_16x16x32_bf16(ak[nb], aqj[0], fzero, 0, 0, 0);
#pragma unroll
            for (int nb = 0; nb < 4; ++nb)
                ak[nb] = *reinterpret_cast<const s16x8*>(c1 + nb * 2048);
#pragma unroll
            for (int nb = 0; nb < 4; ++nb)
                sc2[nb] = __builtin_amdgcn_mfma_f32_16x16x32_bf16(ak[nb], aqj[1], sc2[nb], 0, 0, 0);
        }
        __builtin_amdgcn_s_setprio(0);

        if (domask) {
#pragma unroll
            for (int nb = 0; nb < 4; ++nb)
#pragma unroll
                for (int r = 0; r < 4; ++r)
                    if (nb * 16 + lhi * 4 + r > thr) sc2[nb][r] = -1e30f;
        }

#pragma unroll
        for (int nb = 0; nb < 4; ++nb) {
            float p0 = exp2f(sc2[nb][0]);
            float p1 = exp2f(sc2[nb][1]);
            float p2 = exp2f(sc2[nb][2]);
            float p3 = exp2f(sc2[nb][3]);
            uint2 u;
            u.x = cvtpk(p0, p1);
            u.y = cvtpk(p2, p3);
            *reinterpret_cast<uint2*>(PWp + pw[nb]) = u;
        }

        __builtin_amdgcn_s_setprio(1);
#pragma unroll
        for (int kk = 0; kk < 2; ++kk) {
            s16x8 pa = *reinterpret_cast<const s16x8*>(kk ? pb1 : pb0);
            const char* vb = (kk ? c1 : c0) + 32768;
            s16x8 bvv[4];
#pragma unroll
            for (int nb = 0; nb < 4; ++nb)
                bvv[nb] = *reinterpret_cast<const s16x8*>(vb + nb * 2048);
#pragma unroll
            for (int nb = 0; nb < 4; ++nb)
                o_acc[nb] = __builtin_amdgcn_mfma_f32_16x16x32_bf16(pa, bvv[nb], o_acc[nb], 0, 0, 0);
            l_acc = __builtin_amdgcn_mfma_f32_16x16x32_bf16(pa, onesb, l_acc, 0, 0, 0);
        }
        __builtin_amdgcn_s_setprio(0);
    };

    stage(0);
    __syncthreads();
    int cur = 0;
    const int nt = (33 - bx) >> 1;             // ceil((32-bx)/2) in [13,16]

#pragma unroll 1
    for (int t = 0; t < nt; ++t) {
        if (t + 1 < nt) stage(cur ^ 1);
        const char* kbase = smem + cur * 16384;
#pragma unroll
        for (int st = 0; st < 2; ++st) {
            const int k64 = 2 * t + st;
            const char* c0 = kbase + st * 8192 + kb0;
            const char* c1 = kbase + st * 8192 + kb1;
#pragma unroll
            for (int j = 0; j < 4; ++j)
                if (k64 <= qts[j])
                    tile(aq[j], oA[j], lA[j], k64 == qts[j], c0, c1);
        }
        __syncthreads();
        cur ^= 1;
    }

    // ---- epilogue: zero-shuffle (l rows == o rows) ----
#pragma unroll
    for (int j = 0; j < 4; ++j) {
        float li[4];
#pragma unroll
        for (int r = 0; r < 4; ++r) li[r] = 1.0f / lA[j][r];
#pragma unroll
        for (int nb = 0; nb < 4; ++nb)
#pragma unroll
            for (int r = 0; r < 4; ++r) {
                const int s = qts[j] * 64 + wid * 16 + lhi * 4 + r;
                Ao[((size_t)b * SLEN + s) * DMOD + h * 64 + nb * 16 + l15] =
                    f2bf(oA[j][nb][r] * li[r]);
            }
    }
}

extern "C" void kernel_launch(void* const* d_in, const int* in_sizes, int n_in,
                              void* d_out, int out_size, void* d_ws, size_t ws_size,
                              hipStream_t stream) {
    const float* q  = (const float*)d_in[0];
    const float* k  = (const float*)d_in[1];
    const float* v  = (const float*)d_in[2];
    const float* Wq = (const float*)d_in[4];
    const float* bq = (const float*)d_in[5];
    const float* Wk = (const float*)d_in[6];
    const float* bk = (const float*)d_in[7];
    const float* Wv = (const float*)d_in[8];
    const float* bv = (const float*)d_in[9];
    const float* Wo = (const float*)d_in[10];
    const float* bo = (const float*)d_in[11];

    // ws layout (ushort units): 4 bf16 W's + Q + K + V^T + attn-out = 75 MB.
    unsigned short* wsp = (unsigned short*)d_ws;
    unsigned short* wqc = wsp;
    unsigned short* wkc = wsp + 1048576;
    unsigned short* wvc = wsp + 2097152;
    unsigned short* woc = wsp + 3145728;
    unsigned short* qb  = wsp + 4194304;
    unsigned short* kb  = wsp + 12582912;
    unsigned short* vtb = wsp + 20971520;
    unsigned short* ao  = wsp + 29360128;

    dim3 gb(256);
    convert_w<<<dim3(512), gb, 0, stream>>>(Wq, Wk, Wv, Wo, wsp);
    gemm_qkv<0><<<dim3(512), gb, 0, stream>>>(q, wqc, bq, qb, EXPC);   // Q pre-scaled
    gemm_qkv<0><<<dim3(512), gb, 0, stream>>>(k, wkc, bk, kb, 1.0f);
    gemm_qkv<1><<<dim3(512), gb, 0, stream>>>(v, wvc, bv, vtb, 1.0f);
    attn_kernel<<<dim3(512), gb, 0, stream>>>(qb, kb, vtb, ao);
    gemm_out<<<dim3(512), gb, 0, stream>>>(ao, woc, bo, (float*)d_out);
}

// Round 16
// 170.331 us; speedup vs baseline: 1.0694x; 1.0694x over previous
//
#include <hip/hip_runtime.h>
#include <hip/hip_bf16.h>

// B=4, S=2048, D=1024, H=16, HD=64, causal MHA forward, fp32 in/out.
// Pipeline: convert-W -> 3 QKV GEMMs (fp32 A, 2-deep reg prefetch, counted
// vmcnt barriers) -> flash attn v10 -> out GEMM.

#define SLEN 2048
#define DMOD 1024

typedef __attribute__((ext_vector_type(8))) short s16x8;   // 8 bf16 (4 VGPRs)
typedef __attribute__((ext_vector_type(4))) float f32x4;

__device__ __forceinline__ unsigned short f2bf(float f) {
    union { __hip_bfloat16 h; unsigned short u; } cv;
    cv.h = __float2bfloat16(f);
    return cv.u;
}
__device__ __forceinline__ unsigned cvtpk(float a, float b) {
    unsigned r;
    asm("v_cvt_pk_bf16_f32 %0, %1, %2" : "=v"(r) : "v"(a), "v"(b));
    return r;
}
__device__ __forceinline__ void gload_lds16(const void* g, void* l) {
    __builtin_amdgcn_global_load_lds(
        (const __attribute__((address_space(1))) void*)g,
        (__attribute__((address_space(3))) void*)l, 16, 0, 0);
}

// ---------------- fp32 -> bf16 convert (weights only) --------------------
__global__ __launch_bounds__(256) void convert_w(
    const float* __restrict__ wq, const float* __restrict__ wk,
    const float* __restrict__ wv, const float* __restrict__ wo,
    unsigned short* __restrict__ dst)
{
    const int bid = blockIdx.x, tid = threadIdx.x;
    const int w = bid >> 7;
    const float* src = (w == 0) ? wq : (w == 1) ? wk : (w == 2) ? wv : wo;
    unsigned short* d = dst + (size_t)w * 1048576;
    const size_t off = (size_t)(bid & 127) * 8192;
#pragma unroll
    for (int i = 0; i < 8; ++i) {
        const size_t e = off + (size_t)(i * 256 + tid) * 4;
        float4 x = *reinterpret_cast<const float4*>(&src[e]);
        uint2 u;
        u.x = cvtpk(x.x, x.y);
        u.y = cvtpk(x.z, x.w);
        *reinterpret_cast<uint2*>(&d[e]) = u;
    }
}

// ---------------- QKV GEMM v3: 2-deep A prefetch + counted-vmcnt barrier --
// A fp32 direct (reg-staged, cvt in flight); W bf16 DMA. Per K-step:
//   stageW(t+1) [4 DMA] ; loadA(t+2) [8 loads] ; MFMA(t) ; cvt+ds_write(t+1)
//   ; s_waitcnt vmcnt(8) lgkmcnt(0) ; s_barrier
// vmcnt(8) drains this wave's W-DMA (stage is OLDER than the 8 A-loads) but
// leaves the t+2 A-loads in flight across the barrier -> 2-K-step latency
// cover. Each wave drains its own stage quarter => race-free.
template<int MODE>
__global__ __launch_bounds__(256, 2) void gemm_qkv(
    const float* __restrict__ A, const unsigned short* __restrict__ W,
    const float* __restrict__ bias, unsigned short* __restrict__ outp,
    float oscale)
{
    __shared__ unsigned short Asm[2][8192];
    __shared__ unsigned short Bsm[2][8192];

    const int tid  = threadIdx.x;
    const int lane = tid & 63, wid = tid >> 6;
    const int l15 = lane & 15, lhi = lane >> 4;

    const int flat = blockIdx.x;
    const int logical = (flat & 7) * 64 + (flat >> 3);
    const int m0 = (logical >> 3) * 128, n0 = (logical & 7) * 128;
    const int wr = wid >> 1, wc = wid & 1;

    int soff[4];
    const float* aptc[4];
#pragma unroll
    for (int i = 0; i < 4; ++i) {
        const int f = i * 256 + tid;
        const int srow = f >> 3, sg = f & 7;
        soff[i] = srow * 128 + ((sg ^ (srow & 7)) * 16);
        aptc[i] = A + (size_t)(m0 + srow) * 1024 + sg * 8;
    }
    const int wsrow = lane >> 3;
    const int wsgr  = (lane & 7) ^ wsrow;
    const unsigned short* bpt = W + (size_t)(n0 + wid * 8 + wsrow) * 1024 + wsgr * 8;

    int aoff[2][4], boff[2][4];
#pragma unroll
    for (int kk = 0; kk < 2; ++kk)
#pragma unroll
        for (int i = 0; i < 4; ++i) {
            const int s = ((4 * kk + lhi) ^ (l15 & 7)) * 16;
            aoff[kk][i] = (wr * 64 + i * 16 + l15) * 128 + s;
            boff[kk][i] = (wc * 64 + i * 16 + l15) * 128 + s;
        }

    f32x4 acc[4][4];
#pragma unroll
    for (int i = 0; i < 4; ++i)
#pragma unroll
        for (int j = 0; j < 4; ++j) acc[i][j] = (f32x4)0.f;

    float4 awE[8], awO[8];                     // two in-flight A tiles

    auto loadTo = [&](float4 (&aw)[8], int k0) {
#pragma unroll
        for (int i = 0; i < 4; ++i) {
            aw[2 * i]     = *reinterpret_cast<const float4*>(aptc[i] + k0);
            aw[2 * i + 1] = *reinterpret_cast<const float4*>(aptc[i] + k0 + 4);
        }
    };
    auto writeFrom = [&](float4 (&aw)[8], int bsel) {
#pragma unroll
        for (int i = 0; i < 4; ++i) {
            uint4 u;
            u.x = cvtpk(aw[2 * i].x,     aw[2 * i].y);
            u.y = cvtpk(aw[2 * i].z,     aw[2 * i].w);
            u.z = cvtpk(aw[2 * i + 1].x, aw[2 * i + 1].y);
            u.w = cvtpk(aw[2 * i + 1].z, aw[2 * i + 1].w);
            *reinterpret_cast<uint4*>((char*)&Asm[bsel][0] + soff[i]) = u;
        }
    };
    auto stageW = [&](int bsel) {
        char* bd = (char*)Bsm + bsel * 16384 + wid * 1024;
#pragma unroll
        for (int i = 0; i < 4; ++i)
            gload_lds16(bpt + i * 32768, bd + i * 4096);
        bpt += 64;
    };
    auto mfmaPhase = [&](const char* AB, const char* BB) {
#pragma unroll
        for (int kk = 0; kk < 2; ++kk) {
            s16x8 af[4], bfv[4];
#pragma unroll
            for (int i = 0; i < 4; ++i) af[i]  = *reinterpret_cast<const s16x8*>(AB + aoff[kk][i]);
#pragma unroll
            for (int j = 0; j < 4; ++j) bfv[j] = *reinterpret_cast<const s16x8*>(BB + boff[kk][j]);
#pragma unroll
            for (int i = 0; i < 4; ++i)
#pragma unroll
                for (int j = 0; j < 4; ++j)
                    acc[i][j] = __builtin_amdgcn_mfma_f32_16x16x32_bf16(af[i], bfv[j], acc[i][j], 0, 0, 0);
        }
    };
    auto barrier8 = [&]() {   // drain own W-DMA, keep 8 A-loads in flight
        asm volatile("s_waitcnt vmcnt(8) lgkmcnt(0)" ::: "memory");
        __builtin_amdgcn_s_barrier();
        __builtin_amdgcn_sched_barrier(0);
    };
    auto barrier0 = [&]() {   // tail: full drain
        asm volatile("s_waitcnt vmcnt(0) lgkmcnt(0)" ::: "memory");
        __builtin_amdgcn_s_barrier();
        __builtin_amdgcn_sched_barrier(0);
    };

    // prologue: A0 loaded+written, W0 staged, A1 loads in flight
    loadTo(awE, 0);
    stageW(0);
    writeFrom(awE, 0);      // waits awE (vmcnt<=4), stageW may stay in flight
    loadTo(awO, 64);
    barrier8();             // drains stageW(0); awO(8) stays in flight

#pragma unroll 1
    for (int kt = 0; kt < 16; kt += 2) {
        // EVEN: compute buf0 = tile kt
        if (kt + 1 < 16) stageW(1);                 // W(kt+1), oldest vmem
        if (kt + 2 < 16) loadTo(awE, (kt + 2) * 64);
        mfmaPhase((const char*)&Asm[0][0], (const char*)&Bsm[0][0]);
        if (kt + 1 < 16) writeFrom(awO, 1);         // A(kt+1)
        if (kt + 2 < 16) barrier8(); else barrier0();
        // ODD: compute buf1 = tile kt+1
        if (kt + 2 < 16) stageW(0);                 // W(kt+2)
        if (kt + 3 < 16) loadTo(awO, (kt + 3) * 64);
        mfmaPhase((const char*)&Asm[1][0], (const char*)&Bsm[1][0]);
        if (kt + 2 < 16) writeFrom(awE, 0);         // A(kt+2)
        if (kt + 3 < 16) barrier8(); else barrier0();
    }

#pragma unroll
    for (int j = 0; j < 4; ++j) {
        const int col = n0 + wc * 64 + j * 16 + l15;
        const float bv = bias[col];
#pragma unroll
        for (int i = 0; i < 4; ++i) {
#pragma unroll
            for (int r = 0; r < 4; ++r) {
                const int row = m0 + wr * 64 + i * 16 + lhi * 4 + r;
                const float val = (acc[i][j][r] + bv) * oscale;
                if constexpr (MODE == 0) {
                    outp[(size_t)((row >> 11) * 16 + (col >> 6)) * 131072
                         + (size_t)(row & 2047) * 64 + (col & 63)] = f2bf(val);
                } else {
                    outp[(size_t)((row >> 11) * 16 + (col >> 6)) * 131072
                         + (size_t)(col & 63) * 2048 + (row & 2047)] = f2bf(val);
                }
            }
        }
    }
}

// ---------------- out-proj GEMM (bf16 A via DMA, fp32 out) ---------------
__global__ __launch_bounds__(256) void gemm_out(
    const unsigned short* __restrict__ A, const unsigned short* __restrict__ W,
    const float* __restrict__ bias, float* __restrict__ outp)
{
    __shared__ unsigned short Asm[2][8192];
    __shared__ unsigned short Bsm[2][8192];

    const int tid  = threadIdx.x;
    const int lane = tid & 63, wid = tid >> 6;
    const int l15 = lane & 15, lhi = lane >> 4;

    const int flat = blockIdx.x;
    const int logical = (flat & 7) * 64 + (flat >> 3);
    const int m0 = (logical >> 3) * 128, n0 = (logical & 7) * 128;

    const int wr = wid >> 1, wc = wid & 1;
    const int srow = lane >> 3;
    const int sgr  = (lane & 7) ^ srow;

    int aoff[2][4], boff[2][4];
#pragma unroll
    for (int kk = 0; kk < 2; ++kk)
#pragma unroll
        for (int i = 0; i < 4; ++i) {
            const int s = ((4 * kk + lhi) ^ (l15 & 7)) * 16;
            aoff[kk][i] = (wr * 64 + i * 16 + l15) * 128 + s;
            boff[kk][i] = (wc * 64 + i * 16 + l15) * 128 + s;
        }

    const unsigned short* apt = A + (size_t)(m0 + wid * 8 + srow) * 1024 + sgr * 8;
    const unsigned short* bpt = W + (size_t)(n0 + wid * 8 + srow) * 1024 + sgr * 8;

    f32x4 acc[4][4];
#pragma unroll
    for (int i = 0; i < 4; ++i)
#pragma unroll
        for (int j = 0; j < 4; ++j) acc[i][j] = (f32x4)0.f;

    auto stage = [&](int bsel) {
        char* ad = (char*)Asm + bsel * 16384 + wid * 1024;
        char* bd = (char*)Bsm + bsel * 16384 + wid * 1024;
#pragma unroll
        for (int i = 0; i < 4; ++i) {
            gload_lds16(apt + i * 32768, ad + i * 4096);
            gload_lds16(bpt + i * 32768, bd + i * 4096);
        }
        apt += 64; bpt += 64;
    };

    stage(0);
    __syncthreads();
    int cur = 0;
#pragma unroll 1
    for (int kt = 0; kt < 16; ++kt) {
        if (kt < 15) stage(cur ^ 1);
        const char* AB = (const char*)Asm + cur * 16384;
        const char* BB = (const char*)Bsm + cur * 16384;
#pragma unroll
        for (int kk = 0; kk < 2; ++kk) {
            s16x8 af[4], bfv[4];
#pragma unroll
            for (int i = 0; i < 4; ++i) af[i]  = *reinterpret_cast<const s16x8*>(AB + aoff[kk][i]);
#pragma unroll
            for (int j = 0; j < 4; ++j) bfv[j] = *reinterpret_cast<const s16x8*>(BB + boff[kk][j]);
#pragma unroll
            for (int i = 0; i < 4; ++i)
#pragma unroll
                for (int j = 0; j < 4; ++j)
                    acc[i][j] = __builtin_amdgcn_mfma_f32_16x16x32_bf16(af[i], bfv[j], acc[i][j], 0, 0, 0);
        }
        __syncthreads();
        cur ^= 1;
    }

#pragma unroll
    for (int j = 0; j < 4; ++j) {
        const int col = n0 + wc * 64 + j * 16 + l15;
        const float bv = bias[col];
#pragma unroll
        for (int i = 0; i < 4; ++i)
#pragma unroll
            for (int r = 0; r < 4; ++r) {
                const int row = m0 + wr * 64 + i * 16 + lhi * 4 + r;
                outp[(size_t)row * 1024 + col] = acc[i][j][r] + bv;
            }
    }
}

// ---------------- flash attention v10 (round-13/14 proven, 70.7us) -------
#define EXPC 0.18033688011112043f   // 0.125 * log2(e)

__global__ __launch_bounds__(256, 4) void attn_kernel(
    const unsigned short* __restrict__ Q,
    const unsigned short* __restrict__ Kc,
    const unsigned short* __restrict__ Vt,
    unsigned short* __restrict__ Ao)
{
    // [0,16K): K dbuf  [16K,32K): V^T dbuf  [32K,40K): per-wave P
    __shared__ char smem[40960];

    const int tid = threadIdx.x, lane = tid & 63, wid = tid >> 6;
    const int l15 = lane & 15, lhi = lane >> 4;
    const int sK = l15 & 7;
    const int sub = lane >> 3, c8s = lane & 7;
    const int thr = wid * 16 + l15;

    const int kb0 = l15 * 128 + (lhi ^ sK) * 16;
    const int kb1 = kb0 ^ 64;
    char* const pb0 = smem + 32768 + wid * 2048 + kb0;
    char* const pb1 = smem + 32768 + wid * 2048 + kb1;
    char* const PWp = smem + 32768 + wid * 2048;
    int pw[4];
#pragma unroll
    for (int nb = 0; nb < 4; ++nb)
        pw[nb] = (l15 * 16 + ((nb * 4 + lhi) ^ (2 * sK))) * 8;

    const int flat = blockIdx.x;
    const int logical = (flat & 7) * 128 + (flat >> 3);
    const int bx = logical & 15, bh = logical >> 4;
    const int qtL = bx, qtH = 31 - bx;
    const int q0L = qtL * 64, q0H = qtH * 64;

    const size_t base = (size_t)bh * SLEN * 64;
    const unsigned short* Qb = Q + base;
    const unsigned short* Kb = Kc + base;
    const unsigned short* Vb = Vt + base;      // [64][SLEN]
    const int b = bh >> 4, h = bh & 15;
    const int scol = (c8s ^ sub) * 8;

    const f32x4 fzero = (f32x4)0.f;
    const s16x8 onesb = (s16x8)(short)0x3F80;  // bf16 1.0 splat (l-sum B)

    s16x8 aqL[2], aqH[2];
#pragma unroll
    for (int kk = 0; kk < 2; ++kk) {
        aqL[kk] = *reinterpret_cast<const s16x8*>(
            &Qb[(size_t)(q0L + wid * 16 + l15) * 64 + kk * 32 + 8 * lhi]);
        aqH[kk] = *reinterpret_cast<const s16x8*>(
            &Qb[(size_t)(q0H + wid * 16 + l15) * 64 + kk * 32 + 8 * lhi]);
    }

    f32x4 oL[4], oH[4];
#pragma unroll
    for (int nb = 0; nb < 4; ++nb) { oL[nb] = (f32x4)0.f; oH[nb] = (f32x4)0.f; }
    f32x4 lL = (f32x4)0.f, lH = (f32x4)0.f;

    const unsigned short* kpt = Kb + (16 * wid + sub) * 64 + scol;
    const unsigned short* vpt = Vb + (size_t)(16 * wid + sub) * SLEN + scol;

    auto stage = [&](int bsel) {
        char* kd = smem + bsel * 8192 + wid * 2048;
        char* vd = smem + 16384 + bsel * 8192 + wid * 2048;
        gload_lds16(kpt,         kd);
        gload_lds16(kpt + 512,   kd + 1024);
        gload_lds16(vpt,         vd);
        gload_lds16(vpt + 16384, vd + 1024);
        kpt += 4096; vpt += 64;
    };

    auto tile = [&](s16x8 (&aq)[2], f32x4 (&o_acc)[4], f32x4& l_acc,
                    bool domask, const char* c0, const char* c1) {
        f32x4 sc2[4];
        __builtin_amdgcn_s_setprio(1);
        {
            s16x8 ak[4];
#pragma unroll
            for (int nb = 0; nb < 4; ++nb)
                ak[nb] = *reinterpret_cast<const s16x8*>(c0 + nb * 2048);
#pragma unroll
            for (int nb = 0; nb < 4; ++nb)
                sc2[nb] = __builtin_amdgcn_mfma_f32_16x16x32_bf16(ak[nb], aq[0], fzero, 0, 0, 0);
#pragma unroll
            for (int nb = 0; nb < 4; ++nb)
                ak[nb] = *reinterpret_cast<const s16x8*>(c1 + nb * 2048);
#pragma unroll
            for (int nb = 0; nb < 4; ++nb)
                sc2[nb] = __builtin_amdgcn_mfma_f32_16x16x32_bf16(ak[nb], aq[1], sc2[nb], 0, 0, 0);
        }
        __builtin_amdgcn_s_setprio(0);

        if (domask) {
#pragma unroll
            for (int nb = 0; nb < 4; ++nb)
#pragma unroll
                for (int r = 0; r < 4; ++r)
                    if (nb * 16 + lhi * 4 + r > thr) sc2[nb][r] = -1e30f;
        }

#pragma unroll
        for (int nb = 0; nb < 4; ++nb) {
            float p0 = exp2f(sc2[nb][0]);
            float p1 = exp2f(sc2[nb][1]);
            float p2 = exp2f(sc2[nb][2]);
            float p3 = exp2f(sc2[nb][3]);
            uint2 u;
            u.x = cvtpk(p0, p1);
            u.y = cvtpk(p2, p3);
            *reinterpret_cast<uint2*>(PWp + pw[nb]) = u;
        }

        __builtin_amdgcn_s_setprio(1);
#pragma unroll
        for (int kk = 0; kk < 2; ++kk) {
            s16x8 pa = *reinterpret_cast<const s16x8*>(kk ? pb1 : pb0);
            const char* vb = (kk ? c1 : c0) + 16384;
            s16x8 bvv[4];
#pragma unroll
            for (int nb = 0; nb < 4; ++nb)
                bvv[nb] = *reinterpret_cast<const s16x8*>(vb + nb * 2048);
#pragma unroll
            for (int nb = 0; nb < 4; ++nb)
                o_acc[nb] = __builtin_amdgcn_mfma_f32_16x16x32_bf16(pa, bvv[nb], o_acc[nb], 0, 0, 0);
            l_acc = __builtin_amdgcn_mfma_f32_16x16x32_bf16(pa, onesb, l_acc, 0, 0, 0);
        }
        __builtin_amdgcn_s_setprio(0);
    };

    stage(0);
    __syncthreads();
    int cur = 0;
    const int nt = qtH + 1;

#pragma unroll 1
    for (int t = 0; t < nt; ++t) {
        if (t + 1 < nt) stage(cur ^ 1);
        const char* c0 = smem + cur * 8192 + kb0;
        const char* c1 = smem + cur * 8192 + kb1;
        if (t <= qtL) tile(aqL, oL, lL, t == qtL, c0, c1);
        tile(aqH, oH, lH, t == qtH, c0, c1);
        __syncthreads();
        cur ^= 1;
    }

    float liL[4], liH[4];
#pragma unroll
    for (int r = 0; r < 4; ++r) { liL[r] = 1.0f / lL[r]; liH[r] = 1.0f / lH[r]; }
#pragma unroll
    for (int nb = 0; nb < 4; ++nb)
#pragma unroll
        for (int r = 0; r < 4; ++r) {
            const int sL = q0L + wid * 16 + lhi * 4 + r;
            const int sH = q0H + wid * 16 + lhi * 4 + r;
            const size_t cix = h * 64 + nb * 16 + l15;
            Ao[((size_t)b * SLEN + sL) * DMOD + cix] = f2bf(oL[nb][r] * liL[r]);
            Ao[((size_t)b * SLEN + sH) * DMOD + cix] = f2bf(oH[nb][r] * liH[r]);
        }
}

extern "C" void kernel_launch(void* const* d_in, const int* in_sizes, int n_in,
                              void* d_out, int out_size, void* d_ws, size_t ws_size,
                              hipStream_t stream) {
    const float* q  = (const float*)d_in[0];
    const float* k  = (const float*)d_in[1];
    const float* v  = (const float*)d_in[2];
    const float* Wq = (const float*)d_in[4];
    const float* bq = (const float*)d_in[5];
    const float* Wk = (const float*)d_in[6];
    const float* bk = (const float*)d_in[7];
    const float* Wv = (const float*)d_in[8];
    const float* bv = (const float*)d_in[9];
    const float* Wo = (const float*)d_in[10];
    const float* bo = (const float*)d_in[11];

    // ws layout (ushort units): 4 bf16 W's + Q + K + V^T + attn-out = 75 MB.
    unsigned short* wsp = (unsigned short*)d_ws;
    unsigned short* wqc = wsp;
    unsigned short* wkc = wsp + 1048576;
    unsigned short* wvc = wsp + 2097152;
    unsigned short* woc = wsp + 3145728;
    unsigned short* qb  = wsp + 4194304;
    unsigned short* kb  = wsp + 12582912;
    unsigned short* vtb = wsp + 20971520;
    unsigned short* ao  = wsp + 29360128;

    dim3 gb(256);
    convert_w<<<dim3(512), gb, 0, stream>>>(Wq, Wk, Wv, Wo, wsp);
    gemm_qkv<0><<<dim3(512), gb, 0, stream>>>(q, wqc, bq, qb, EXPC);   // Q pre-scaled
    gemm_qkv<0><<<dim3(512), gb, 0, stream>>>(k, wkc, bk, kb, 1.0f);
    gemm_qkv<1><<<dim3(512), gb, 0, stream>>>(v, wvc, bv, vtb, 1.0f);
    attn_kernel<<<dim3(1024), gb, 0, stream>>>(qb, kb, vtb, ao);
    gemm_out<<<dim3(512), gb, 0, stream>>>(ao, woc, bo, (float*)d_out);
}